// Round 15
// baseline (339.682 us; speedup 1.0000x reference)
//
#include <hip/hip_runtime.h>
#include <hip/hip_bf16.h>

// Flash-attention forward, B=4 H=16 S=2048 D=128, fp32 in/out, no 1/sqrt(D) scale.
// Round 14: revert R13's dbuf (occupancy loss beat pipelining). R12 structure, but
//   QBLK=128: each wave owns 32 q-rows as TWO sequential 16-row subtiles.
//   Staging events + barriers per unit work halve; LDS stays 40960 (4 blocks/CU);
//   grid 1024 = exactly 4/CU. VGPR ~120 under launch_bounds(256,4).
//   Keeps: pre-pass (K swz / V^T swz), gload_lds staging, swapped QK^T softmax,
//   T13 defer-max, XCD-gather, all-b128 LDS reads, setprio.

#define QBLK   128
#define KVBLK  64
#define DHEAD  128
#define SEQ    2048
#define NT     (SEQ / KVBLK)
#define KPAD   136   // legacy kernel only
#define PPAD   72    // legacy kernel only
#define RESCALE_THR 8.0f

typedef _Float16 f16x8 __attribute__((ext_vector_type(8)));
typedef _Float16 f16x4 __attribute__((ext_vector_type(4)));
typedef float    f32x4 __attribute__((ext_vector_type(4)));

#define AS1P(x) ((const __attribute__((address_space(1))) void*)(size_t)(x))
#define AS3P(x) ((__attribute__((address_space(3))) void*)(unsigned long long)(unsigned)(size_t)(x))

// ---------------- pre-pass: fp32 -> fp16, LDS-linear tile layouts ----------------
__global__ __launch_bounds__(256)
void preconv_kernel(const float* __restrict__ K, const float* __restrict__ V,
                    _Float16* __restrict__ Kp, _Float16* __restrict__ Vp) {
    const int bt = blockIdx.x;                       // bh*32 + t (tiles contiguous)
    const size_t src = (size_t)bt * (KVBLK * DHEAD);
    const float* Kt = K + src;
    const float* Vt = V + src;
    _Float16* Ko = Kp + src;
    _Float16* Vo = Vp + src;
    #pragma unroll
    for (int j = 0; j < 4; ++j) {
        const int c = threadIdx.x + 256 * j;         // 0..1023
        // K: row-major [kv][d], XOR-swizzled at 8-element granule
        {
            const int row = c >> 4;
            const int d0  = (c & 15) * 8;
            float4 f0 = *(const float4*)(Kt + row * DHEAD + d0);
            float4 f1 = *(const float4*)(Kt + row * DHEAD + d0 + 4);
            f16x8 h;
            h[0]=(_Float16)f0.x; h[1]=(_Float16)f0.y; h[2]=(_Float16)f0.z; h[3]=(_Float16)f0.w;
            h[4]=(_Float16)f1.x; h[5]=(_Float16)f1.y; h[6]=(_Float16)f1.z; h[7]=(_Float16)f1.w;
            *(f16x8*)&Ko[row * 128 + (d0 ^ ((row & 7) << 3))] = h;
        }
        // V^T: [d][kv], kv-granule XOR-swizzled by d-row (read path == K path)
        {
            const int d   = c & 127;                 // coalesced across lanes per i
            const int kvg = c >> 7;                  // 0..7
            f16x8 h;
            #pragma unroll
            for (int i = 0; i < 8; ++i)
                h[i] = (_Float16)Vt[(kvg * 8 + i) * DHEAD + d];
            *(f16x8*)&Vo[d * 64 + ((kvg * 8) ^ ((d & 7) << 3))] = h;
        }
    }
}

// ---------------- main kernel: gload_lds staging, 2 q-subtiles per wave ----------------
__global__ __launch_bounds__(256, 4)
void attn_fwd_kernel(const float* __restrict__ Q, const _Float16* __restrict__ Kp,
                     const _Float16* __restrict__ Vp, float* __restrict__ O) {
    __shared__ __align__(16) _Float16 K_lds[KVBLK * DHEAD];   // [kv][d] + XOR swizzle
    __shared__ __align__(16) _Float16 V_lds[KVBLK * DHEAD];   // [d][kv] + XOR swizzle
    __shared__ __align__(16) _Float16 P_lds[4 * 16 * 64];     // per-wave region, reused per subtile

    const int tid  = threadIdx.x;
    const int lane = tid & 63;
    const int wave = tid >> 6;
    const int g    = lane >> 4;
    const int lg   = lane & 15;

    // XCD-gather swizzle (1024 blocks = 8 * 128)
    const int flat    = blockIdx.x + gridDim.x * blockIdx.y;
    const int newflat = (flat & 7) * 128 + (flat >> 3);
    const int qtile   = newflat & 15;
    const int bh      = newflat >> 4;

    const float* Qg = Q + (size_t)bh * SEQ * DHEAD + (size_t)(qtile * QBLK) * DHEAD;
    float*       Og = O + (size_t)bh * SEQ * DHEAD + (size_t)(qtile * QBLK) * DHEAD;

    // ---- Q fragments (fp16), 2 subtiles. Frag layout: idx=lane&15, k=(lane>>4)*8+i
    f16x8 qf[2][4];
    #pragma unroll
    for (int sub = 0; sub < 2; ++sub) {
        const float* qrow = Qg + (size_t)(wave * 32 + sub * 16 + lg) * DHEAD;
        #pragma unroll
        for (int dc = 0; dc < 4; ++dc) {
            const int d0 = dc * 32 + g * 8;
            float4 f0 = *(const float4*)(qrow + d0);
            float4 f1 = *(const float4*)(qrow + d0 + 4);
            qf[sub][dc][0] = (_Float16)f0.x; qf[sub][dc][1] = (_Float16)f0.y;
            qf[sub][dc][2] = (_Float16)f0.z; qf[sub][dc][3] = (_Float16)f0.w;
            qf[sub][dc][4] = (_Float16)f1.x; qf[sub][dc][5] = (_Float16)f1.y;
            qf[sub][dc][6] = (_Float16)f1.z; qf[sub][dc][7] = (_Float16)f1.w;
        }
    }

    f32x4 acc[2][8];
    #pragma unroll
    for (int sub = 0; sub < 2; ++sub)
        #pragma unroll
        for (int dt = 0; dt < 8; ++dt) { acc[sub][dt][0]=0.f; acc[sub][dt][1]=0.f; acc[sub][dt][2]=0.f; acc[sub][dt][3]=0.f; }
    float m[2] = {-1e30f, -1e30f}, l[2] = {0.f, 0.f};

    for (int t = 0; t < NT; ++t) {
        // ---- stage K+V: 8 global_load_lds dwordx4 per wave, zero VALU
        {
            const _Float16* Ktile = Kp + (size_t)(bh * 32 + t) * (KVBLK * DHEAD);
            const _Float16* Vtile = Vp + (size_t)(bh * 32 + t) * (KVBLK * DHEAD);
            #pragma unroll
            for (int i = 0; i < 4; ++i) {
                const int eoff = wave * 2048 + i * 512;
                __builtin_amdgcn_global_load_lds(AS1P(Ktile + eoff + lane * 8),
                                                 AS3P(&K_lds[eoff]), 16, 0, 0);
                __builtin_amdgcn_global_load_lds(AS1P(Vtile + eoff + lane * 8),
                                                 AS3P(&V_lds[eoff]), 16, 0, 0);
            }
        }
        __syncthreads();   // vmcnt drain

        #pragma unroll
        for (int sub = 0; sub < 2; ++sub) {
            // ---- S^T = mfma(K, Q_sub): lane holds S[kv=ct*16+g*4+r][q-row=lg]
            f32x4 s[4];
            __builtin_amdgcn_s_setprio(1);
            #pragma unroll
            for (int ct = 0; ct < 4; ++ct) {
                f32x4 a; a[0]=0.f; a[1]=0.f; a[2]=0.f; a[3]=0.f;
                #pragma unroll
                for (int dc = 0; dc < 4; ++dc) {
                    const int krow = ct * 16 + lg;
                    const int off  = krow * 128 + ((dc * 32 + g * 8) ^ ((krow & 7) << 3));
                    f16x8 kh = *(const f16x8*)&K_lds[off];
                    a = __builtin_amdgcn_mfma_f32_16x16x32_f16(kh, qf[sub][dc], a, 0, 0, 0);
                }
                s[ct] = a;
            }
            __builtin_amdgcn_s_setprio(0);

            // ---- online softmax with T13 defer-max
            float pmax = s[0][0];
            #pragma unroll
            for (int ct = 0; ct < 4; ++ct)
                #pragma unroll
                for (int r = 0; r < 4; ++r)
                    pmax = fmaxf(pmax, s[ct][r]);
            pmax = fmaxf(pmax, __shfl_xor(pmax, 16));
            pmax = fmaxf(pmax, __shfl_xor(pmax, 32));

            if (!__all(pmax - m[sub] <= RESCALE_THR)) {
                const float mnew = fmaxf(m[sub], pmax);
                const float sc   = __expf(m[sub] - mnew);
                m[sub] = mnew;
                l[sub] *= sc;
                #pragma unroll
                for (int r = 0; r < 4; ++r) {
                    const float scr = __shfl(sc, g * 20 + r);
                    #pragma unroll
                    for (int dt = 0; dt < 8; ++dt) acc[sub][dt][r] *= scr;
                }
            }
            float rs = 0.f;
            #pragma unroll
            for (int ct = 0; ct < 4; ++ct)
                #pragma unroll
                for (int r = 0; r < 4; ++r) {
                    float p = __expf(s[ct][r] - m[sub]);
                    s[ct][r] = p;
                    rs += p;
                }
            rs += __shfl_xor(rs, 16);
            rs += __shfl_xor(rs, 32);
            l[sub] += rs;

            // ---- P -> LDS (per-wave region, reused across subtiles)
            _Float16* pbase = &P_lds[wave * 16 * 64];
            #pragma unroll
            for (int ct = 0; ct < 4; ++ct) {
                f16x4 pk;
                pk[0] = (_Float16)s[ct][0]; pk[1] = (_Float16)s[ct][1];
                pk[2] = (_Float16)s[ct][2]; pk[3] = (_Float16)s[ct][3];
                *(f16x4*)&pbase[lg * 64 + ((ct * 16 + g * 4) ^ ((lg & 7) << 3))] = pk;
            }

            // ---- O += P * V
            __builtin_amdgcn_s_setprio(1);
            #pragma unroll
            for (int kt = 0; kt < 2; ++kt) {
                const int koff = (kt * 32 + g * 8) ^ ((lg & 7) << 3);
                f16x8 pf = *(const f16x8*)&pbase[lg * 64 + koff];
                #pragma unroll
                for (int dt = 0; dt < 8; ++dt) {
                    f16x8 vf = *(const f16x8*)&V_lds[(dt * 16 + lg) * 64 + koff];
                    acc[sub][dt] = __builtin_amdgcn_mfma_f32_16x16x32_f16(pf, vf, acc[sub][dt], 0, 0, 0);
                }
            }
            __builtin_amdgcn_s_setprio(0);
        }
        __syncthreads();
    }

    // ---- epilogue (both subtiles)
    #pragma unroll
    for (int sub = 0; sub < 2; ++sub) {
        const float linv = 1.f / l[sub];
        float inv[4];
        #pragma unroll
        for (int r = 0; r < 4; ++r) inv[r] = __shfl(linv, g * 20 + r);
        float* ob = Og + (size_t)(wave * 32 + sub * 16) * DHEAD;
        #pragma unroll
        for (int dt = 0; dt < 8; ++dt)
            #pragma unroll
            for (int r = 0; r < 4; ++r)
                ob[(size_t)(g * 4 + r) * DHEAD + dt * 16 + lg] = acc[sub][dt][r] * inv[r];
    }
}

// ---------------- legacy (R9) kernel: fallback when ws too small ----------------
__global__ __launch_bounds__(256, 3)
void attn_fwd_legacy(const float* __restrict__ Q, const float* __restrict__ K,
                     const float* __restrict__ V, float* __restrict__ O) {
    __shared__ __align__(16) _Float16 K_lds[KVBLK * KPAD];
    __shared__ __align__(16) _Float16 V_lds[KVBLK * DHEAD];
    __shared__ __align__(16) _Float16 P_lds[4 * 16 * PPAD];

    const int tid  = threadIdx.x;
    const int lane = tid & 63;
    const int wave = tid >> 6;
    const int g    = lane >> 4;
    const int lg   = lane & 15;

    const int flat    = blockIdx.x + gridDim.x * blockIdx.y;   // 0..2047
    const int newflat = (flat & 7) * 256 + (flat >> 3);
    const int qtile   = newflat & 31;
    const int bh      = newflat >> 5;

    const size_t base = (size_t)bh * SEQ * DHEAD;
    const float* Qg = Q + base + (size_t)(qtile * 64) * DHEAD;
    const float* Kg = K + base;
    const float* Vg = V + base;
    float*       Og = O + base + (size_t)(qtile * 64) * DHEAD;

    const unsigned trbase = (unsigned)(size_t)&V_lds[0] + (unsigned)(g * 2048 + lg * 8);

    f16x8 qf[4];
    {
        const float* qrow = Qg + (size_t)(wave * 16 + lg) * DHEAD;
        #pragma unroll
        for (int dc = 0; dc < 4; ++dc) {
            const int d0 = dc * 32 + g * 8;
            float4 f0 = *(const float4*)(qrow + d0);
            float4 f1 = *(const float4*)(qrow + d0 + 4);
            qf[dc][0] = (_Float16)f0.x; qf[dc][1] = (_Float16)f0.y;
            qf[dc][2] = (_Float16)f0.z; qf[dc][3] = (_Float16)f0.w;
            qf[dc][4] = (_Float16)f1.x; qf[dc][5] = (_Float16)f1.y;
            qf[dc][6] = (_Float16)f1.z; qf[dc][7] = (_Float16)f1.w;
        }
    }

    f32x4 acc[8];
    #pragma unroll
    for (int dt = 0; dt < 8; ++dt) { acc[dt][0]=0.f; acc[dt][1]=0.f; acc[dt][2]=0.f; acc[dt][3]=0.f; }
    float m = -1e30f, l = 0.f;

    for (int t = 0; t < NT; ++t) {
        {
            const float* Kt = Kg + (size_t)t * KVBLK * DHEAD;
            #pragma unroll
            for (int j = 0; j < 4; ++j) {
                const int c   = tid + 256 * j;
                const int row = c >> 4;
                const int dc  = (c & 15) * 8;
                float4 f0 = *(const float4*)(Kt + row * DHEAD + dc);
                float4 f1 = *(const float4*)(Kt + row * DHEAD + dc + 4);
                f16x8 vh;
                vh[0]=(_Float16)f0.x; vh[1]=(_Float16)f0.y; vh[2]=(_Float16)f0.z; vh[3]=(_Float16)f0.w;
                vh[4]=(_Float16)f1.x; vh[5]=(_Float16)f1.y; vh[6]=(_Float16)f1.z; vh[7]=(_Float16)f1.w;
                *(f16x8*)&K_lds[row * KPAD + dc] = vh;
            }
            const float* Vt = Vg + (size_t)t * KVBLK * DHEAD;
            #pragma unroll
            for (int j = 0; j < 4; ++j) {
                const int c   = tid + 256 * j;
                const int d8  = (c & 1) | (((c >> 3) & 7) << 1);
                const int row = ((c >> 1) & 3) | ((c >> 6) << 2);
                const int d0  = d8 * 8;
                float4 f0 = *(const float4*)(Vt + row * DHEAD + d0);
                float4 f1 = *(const float4*)(Vt + row * DHEAD + d0 + 4);
                f16x8 vv;
                vv[0]=(_Float16)f0.x; vv[1]=(_Float16)f0.y; vv[2]=(_Float16)f0.z; vv[3]=(_Float16)f0.w;
                vv[4]=(_Float16)f1.x; vv[5]=(_Float16)f1.y; vv[6]=(_Float16)f1.z; vv[7]=(_Float16)f1.w;
                const int st = (row >> 2) * 8 + (d0 >> 4);
                *(f16x8*)&V_lds[st * 64 + (row & 3) * 16 + (d0 & 15)] = vv;
            }
        }
        __syncthreads();

        f32x4 s[4];
        __builtin_amdgcn_s_setprio(1);
        #pragma unroll
        for (int ct = 0; ct < 4; ++ct) {
            f32x4 a; a[0]=0.f; a[1]=0.f; a[2]=0.f; a[3]=0.f;
            #pragma unroll
            for (int dc = 0; dc < 4; ++dc) {
                const int off = (ct * 16 + lg) * KPAD + dc * 32 + g * 8;
                f16x8 kh = *(const f16x8*)&K_lds[off];
                a = __builtin_amdgcn_mfma_f32_16x16x32_f16(kh, qf[dc], a, 0, 0, 0);
            }
            s[ct] = a;
        }
        __builtin_amdgcn_s_setprio(0);

        float pmax = s[0][0];
        #pragma unroll
        for (int ct = 0; ct < 4; ++ct)
            #pragma unroll
            for (int r = 0; r < 4; ++r)
                pmax = fmaxf(pmax, s[ct][r]);
        pmax = fmaxf(pmax, __shfl_xor(pmax, 16));
        pmax = fmaxf(pmax, __shfl_xor(pmax, 32));
        const float mnew = fmaxf(m, pmax);
        const float sc   = __expf(m - mnew);
        m = mnew;
        float rs = 0.f;
        #pragma unroll
        for (int ct = 0; ct < 4; ++ct)
            #pragma unroll
            for (int r = 0; r < 4; ++r) {
                float p = __expf(s[ct][r] - mnew);
                s[ct][r] = p;
                rs += p;
            }
        rs += __shfl_xor(rs, 16);
        rs += __shfl_xor(rs, 32);
        l = l * sc + rs;

        #pragma unroll
        for (int r = 0; r < 4; ++r) {
            const float scr = __shfl(sc, g * 20 + r);
            #pragma unroll
            for (int dt = 0; dt < 8; ++dt) acc[dt][r] *= scr;
        }

        _Float16* pbase = &P_lds[wave * 16 * PPAD];
        #pragma unroll
        for (int ct = 0; ct < 4; ++ct) {
            f16x4 pk;
            pk[0] = (_Float16)s[ct][0]; pk[1] = (_Float16)s[ct][1];
            pk[2] = (_Float16)s[ct][2]; pk[3] = (_Float16)s[ct][3];
            *(f16x4*)&pbase[lg * PPAD + ct * 16 + g * 4] = pk;
        }

        #pragma unroll
        for (int kt = 0; kt < 2; ++kt) {
            f16x8 pf = *(const f16x8*)&pbase[lg * PPAD + kt * 32 + g * 8];
            #pragma unroll
            for (int dp = 0; dp < 4; ++dp) {
                f16x4 a0, a1, b0, b1;
                asm volatile(
                    "ds_read_b64_tr_b16 %0, %4 offset:%5\n\t"
                    "ds_read_b64_tr_b16 %1, %4 offset:%6\n\t"
                    "ds_read_b64_tr_b16 %2, %4 offset:%7\n\t"
                    "ds_read_b64_tr_b16 %3, %4 offset:%8\n\t"
                    "s_waitcnt lgkmcnt(0)"
                    : "=&v"(a0), "=&v"(a1), "=&v"(b0), "=&v"(b1)
                    : "v"(trbase),
                      "i"(kt * 8192 + (dp * 2 + 0) * 128),
                      "i"(kt * 8192 + 1024 + (dp * 2 + 0) * 128),
                      "i"(kt * 8192 + (dp * 2 + 1) * 128),
                      "i"(kt * 8192 + 1024 + (dp * 2 + 1) * 128)
                    : "memory");
                __builtin_amdgcn_sched_barrier(0);
                f16x8 vf0 = __builtin_shufflevector(a0, a1, 0, 1, 2, 3, 4, 5, 6, 7);
                f16x8 vf1 = __builtin_shufflevector(b0, b1, 0, 1, 2, 3, 4, 5, 6, 7);
                __builtin_amdgcn_s_setprio(1);
                acc[dp * 2 + 0] = __builtin_amdgcn_mfma_f32_16x16x32_f16(pf, vf0, acc[dp * 2 + 0], 0, 0, 0);
                acc[dp * 2 + 1] = __builtin_amdgcn_mfma_f32_16x16x32_f16(pf, vf1, acc[dp * 2 + 1], 0, 0, 0);
                __builtin_amdgcn_s_setprio(0);
            }
        }
        __syncthreads();
    }

    const float linv = 1.f / l;
    float inv[4];
    #pragma unroll
    for (int r = 0; r < 4; ++r) inv[r] = __shfl(linv, g * 20 + r);
    float* ob = Og + (size_t)(wave * 16) * DHEAD;
    #pragma unroll
    for (int dt = 0; dt < 8; ++dt)
        #pragma unroll
        for (int r = 0; r < 4; ++r)
            ob[(size_t)(g * 4 + r) * DHEAD + dt * 16 + lg] = acc[dt][r] * inv[r];
}

extern "C" void kernel_launch(void* const* d_in, const int* in_sizes, int n_in,
                              void* d_out, int out_size, void* d_ws, size_t ws_size,
                              hipStream_t stream) {
    const float* q = (const float*)d_in[0];
    const float* k = (const float*)d_in[1];
    const float* v = (const float*)d_in[2];
    float* out = (float*)d_out;
    const int BH = in_sizes[0] / (SEQ * DHEAD);   // 64

    const size_t elems = (size_t)BH * SEQ * DHEAD;           // 16M
    const size_t need  = elems * 2 * sizeof(_Float16);       // 64 MB
    if (ws_size >= need) {
        _Float16* Kp = (_Float16*)d_ws;
        _Float16* Vp = Kp + elems;
        preconv_kernel<<<dim3(BH * (SEQ / KVBLK)), dim3(256), 0, stream>>>(k, v, Kp, Vp);
        attn_fwd_kernel<<<dim3(SEQ / QBLK, BH), dim3(256), 0, stream>>>(q, Kp, Vp, out);
    } else {
        attn_fwd_legacy<<<dim3(SEQ / 64, BH), dim3(256), 0, stream>>>(q, k, v, out);
    }
}

// Round 16
// 222.397 us; speedup vs baseline: 1.5274x; 1.5274x over previous
//
#include <hip/hip_runtime.h>
#include <hip/hip_bf16.h>

// Flash-attention forward, B=4 H=16 S=2048 D=128, fp32 in/out, no 1/sqrt(D) scale.
// Round 15: revert R14 (spill). 8-wave (512-thread) blocks, QBLK=128 (16 rows/wave,
//   per-wave structure identical to R12) + DOUBLE-BUFFERED K/V:
//   LDS = 2*16K + 2*16K + 16K = 81920 -> 2 blocks/CU -> 16 waves/CU (same as R12),
//   1 barrier/tile, staging per wave halved, drain hidden under compute.
//   Keeps: pre-pass (K swz / V^T swz), gload_lds staging, swapped QK^T softmax,
//   T13 defer-max, XCD-gather, all-b128 LDS reads, setprio.

#define QBLK   128
#define KVBLK  64
#define DHEAD  128
#define SEQ    2048
#define NT     (SEQ / KVBLK)
#define KPAD   136   // legacy kernel only
#define PPAD   72    // legacy kernel only
#define RESCALE_THR 8.0f

typedef _Float16 f16x8 __attribute__((ext_vector_type(8)));
typedef _Float16 f16x4 __attribute__((ext_vector_type(4)));
typedef float    f32x4 __attribute__((ext_vector_type(4)));

#define AS1P(x) ((const __attribute__((address_space(1))) void*)(size_t)(x))
#define AS3P(x) ((__attribute__((address_space(3))) void*)(unsigned long long)(unsigned)(size_t)(x))

// ---------------- pre-pass: fp32 -> fp16, LDS-linear tile layouts ----------------
__global__ __launch_bounds__(256)
void preconv_kernel(const float* __restrict__ K, const float* __restrict__ V,
                    _Float16* __restrict__ Kp, _Float16* __restrict__ Vp) {
    const int bt = blockIdx.x;                       // bh*32 + t (tiles contiguous)
    const size_t src = (size_t)bt * (KVBLK * DHEAD);
    const float* Kt = K + src;
    const float* Vt = V + src;
    _Float16* Ko = Kp + src;
    _Float16* Vo = Vp + src;
    #pragma unroll
    for (int j = 0; j < 4; ++j) {
        const int c = threadIdx.x + 256 * j;         // 0..1023
        // K: row-major [kv][d], XOR-swizzled at 8-element granule
        {
            const int row = c >> 4;
            const int d0  = (c & 15) * 8;
            float4 f0 = *(const float4*)(Kt + row * DHEAD + d0);
            float4 f1 = *(const float4*)(Kt + row * DHEAD + d0 + 4);
            f16x8 h;
            h[0]=(_Float16)f0.x; h[1]=(_Float16)f0.y; h[2]=(_Float16)f0.z; h[3]=(_Float16)f0.w;
            h[4]=(_Float16)f1.x; h[5]=(_Float16)f1.y; h[6]=(_Float16)f1.z; h[7]=(_Float16)f1.w;
            *(f16x8*)&Ko[row * 128 + (d0 ^ ((row & 7) << 3))] = h;
        }
        // V^T: [d][kv], kv-granule XOR-swizzled by d-row (read path == K path)
        {
            const int d   = c & 127;                 // coalesced across lanes per i
            const int kvg = c >> 7;                  // 0..7
            f16x8 h;
            #pragma unroll
            for (int i = 0; i < 8; ++i)
                h[i] = (_Float16)Vt[(kvg * 8 + i) * DHEAD + d];
            *(f16x8*)&Vo[d * 64 + ((kvg * 8) ^ ((d & 7) << 3))] = h;
        }
    }
}

// ---------------- main kernel: 8-wave block, dbuf gload_lds staging ----------------
__global__ __launch_bounds__(512, 2)
void attn_fwd_kernel(const float* __restrict__ Q, const _Float16* __restrict__ Kp,
                     const _Float16* __restrict__ Vp, float* __restrict__ O) {
    __shared__ __align__(16) _Float16 K_lds[2][KVBLK * DHEAD];   // [kv][d] + XOR swizzle
    __shared__ __align__(16) _Float16 V_lds[2][KVBLK * DHEAD];   // [d][kv] + XOR swizzle
    __shared__ __align__(16) _Float16 P_lds[8 * 16 * 64];        // per-wave regions

    const int tid  = threadIdx.x;
    const int lane = tid & 63;
    const int wave = tid >> 6;          // 0..7
    const int g    = lane >> 4;
    const int lg   = lane & 15;

    // XCD-gather swizzle (1024 blocks = 8 * 128)
    const int flat    = blockIdx.x + gridDim.x * blockIdx.y;
    const int newflat = (flat & 7) * 128 + (flat >> 3);
    const int qtile   = newflat & 15;   // 16 q-tiles of 128 rows
    const int bh      = newflat >> 4;

    const float* Qg = Q + (size_t)bh * SEQ * DHEAD + (size_t)(qtile * QBLK) * DHEAD;
    float*       Og = O + (size_t)bh * SEQ * DHEAD + (size_t)(qtile * QBLK) * DHEAD;

    // ---- Q fragments (fp16). Frag layout: idx=lane&15, k=(lane>>4)*8+i
    f16x8 qf[4];
    {
        const float* qrow = Qg + (size_t)(wave * 16 + lg) * DHEAD;
        #pragma unroll
        for (int dc = 0; dc < 4; ++dc) {
            const int d0 = dc * 32 + g * 8;
            float4 f0 = *(const float4*)(qrow + d0);
            float4 f1 = *(const float4*)(qrow + d0 + 4);
            qf[dc][0] = (_Float16)f0.x; qf[dc][1] = (_Float16)f0.y;
            qf[dc][2] = (_Float16)f0.z; qf[dc][3] = (_Float16)f0.w;
            qf[dc][4] = (_Float16)f1.x; qf[dc][5] = (_Float16)f1.y;
            qf[dc][6] = (_Float16)f1.z; qf[dc][7] = (_Float16)f1.w;
        }
    }

    f32x4 acc[8];
    #pragma unroll
    for (int dt = 0; dt < 8; ++dt) { acc[dt][0]=0.f; acc[dt][1]=0.f; acc[dt][2]=0.f; acc[dt][3]=0.f; }
    float m = -1e30f, l = 0.f;

    // 8 waves share each tile: 2 gload_lds calls per wave per buffer (K and V)
    #define STAGE(B, T) {                                                          \
        const _Float16* Ktile = Kp + (size_t)(bh * 32 + (T)) * (KVBLK * DHEAD);    \
        const _Float16* Vtile = Vp + (size_t)(bh * 32 + (T)) * (KVBLK * DHEAD);    \
        _Pragma("unroll")                                                          \
        for (int i = 0; i < 2; ++i) {                                              \
            const int eoff = wave * 1024 + i * 512;                                \
            __builtin_amdgcn_global_load_lds(AS1P(Ktile + eoff + lane * 8),        \
                                             AS3P(&K_lds[B][eoff]), 16, 0, 0);     \
            __builtin_amdgcn_global_load_lds(AS1P(Vtile + eoff + lane * 8),        \
                                             AS3P(&V_lds[B][eoff]), 16, 0, 0);     \
        }                                                                          \
    }

    #define COMPUTE(B) {                                                           \
        f32x4 s[4];                                                                \
        __builtin_amdgcn_s_setprio(1);                                             \
        _Pragma("unroll")                                                          \
        for (int ct = 0; ct < 4; ++ct) {                                           \
            f32x4 a; a[0]=0.f; a[1]=0.f; a[2]=0.f; a[3]=0.f;                       \
            _Pragma("unroll")                                                      \
            for (int dc = 0; dc < 4; ++dc) {                                       \
                const int krow = ct * 16 + lg;                                     \
                const int ko = krow * 128 + ((dc * 32 + g * 8) ^ ((krow & 7) << 3)); \
                f16x8 kh = *(const f16x8*)&K_lds[B][ko];                           \
                a = __builtin_amdgcn_mfma_f32_16x16x32_f16(kh, qf[dc], a, 0, 0, 0);\
            }                                                                      \
            s[ct] = a;                                                             \
        }                                                                          \
        __builtin_amdgcn_s_setprio(0);                                             \
        float pmax = s[0][0];                                                      \
        _Pragma("unroll")                                                          \
        for (int ct = 0; ct < 4; ++ct)                                             \
            _Pragma("unroll")                                                      \
            for (int r = 0; r < 4; ++r)                                            \
                pmax = fmaxf(pmax, s[ct][r]);                                      \
        pmax = fmaxf(pmax, __shfl_xor(pmax, 16));                                  \
        pmax = fmaxf(pmax, __shfl_xor(pmax, 32));                                  \
        if (!__all(pmax - m <= RESCALE_THR)) {                                     \
            const float mnew = fmaxf(m, pmax);                                     \
            const float sc   = __expf(m - mnew);                                   \
            m = mnew;                                                              \
            l *= sc;                                                               \
            _Pragma("unroll")                                                      \
            for (int r = 0; r < 4; ++r) {                                          \
                const float scr = __shfl(sc, g * 20 + r);                          \
                _Pragma("unroll")                                                  \
                for (int dt = 0; dt < 8; ++dt) acc[dt][r] *= scr;                  \
            }                                                                      \
        }                                                                          \
        float rs = 0.f;                                                            \
        _Pragma("unroll")                                                          \
        for (int ct = 0; ct < 4; ++ct)                                             \
            _Pragma("unroll")                                                      \
            for (int r = 0; r < 4; ++r) {                                          \
                float p = __expf(s[ct][r] - m);                                    \
                s[ct][r] = p;                                                      \
                rs += p;                                                           \
            }                                                                      \
        rs += __shfl_xor(rs, 16);                                                  \
        rs += __shfl_xor(rs, 32);                                                  \
        l += rs;                                                                   \
        _Float16* pbase = &P_lds[wave * 16 * 64];                                  \
        _Pragma("unroll")                                                          \
        for (int ct = 0; ct < 4; ++ct) {                                           \
            f16x4 pk;                                                              \
            pk[0] = (_Float16)s[ct][0]; pk[1] = (_Float16)s[ct][1];                \
            pk[2] = (_Float16)s[ct][2]; pk[3] = (_Float16)s[ct][3];                \
            *(f16x4*)&pbase[lg * 64 + ((ct * 16 + g * 4) ^ ((lg & 7) << 3))] = pk; \
        }                                                                          \
        __builtin_amdgcn_s_setprio(1);                                             \
        _Pragma("unroll")                                                          \
        for (int kt = 0; kt < 2; ++kt) {                                           \
            const int koff = (kt * 32 + g * 8) ^ ((lg & 7) << 3);                  \
            f16x8 pf = *(const f16x8*)&pbase[lg * 64 + koff];                      \
            _Pragma("unroll")                                                      \
            for (int dt = 0; dt < 8; ++dt) {                                       \
                f16x8 vf = *(const f16x8*)&V_lds[B][(dt * 16 + lg) * 64 + koff];   \
                acc[dt] = __builtin_amdgcn_mfma_f32_16x16x32_f16(pf, vf, acc[dt], 0, 0, 0); \
            }                                                                      \
        }                                                                          \
        __builtin_amdgcn_s_setprio(0);                                             \
    }

    // prologue: stage tile 0 into buffer 0
    STAGE(0, 0);
    __syncthreads();

    // main loop: 2 tiles per iteration, compile-time buffer indices, 1 barrier/tile
    #pragma unroll 1
    for (int tt = 0; tt < NT / 2; ++tt) {
        const int t0 = tt * 2;
        STAGE(1, t0 + 1);            // prefetch into buf1 while computing buf0
        COMPUTE(0);
        __syncthreads();             // drain lands after a full compute phase
        if (t0 + 2 < NT) STAGE(0, t0 + 2);
        COMPUTE(1);
        __syncthreads();
    }

    #undef STAGE
    #undef COMPUTE

    // ---- epilogue
    const float linv = 1.f / l;
    float inv[4];
    #pragma unroll
    for (int r = 0; r < 4; ++r) inv[r] = __shfl(linv, g * 20 + r);
    float* ob = Og + (size_t)(wave * 16) * DHEAD;
    #pragma unroll
    for (int dt = 0; dt < 8; ++dt)
        #pragma unroll
        for (int r = 0; r < 4; ++r)
            ob[(size_t)(g * 4 + r) * DHEAD + dt * 16 + lg] = acc[dt][r] * inv[r];
}

// ---------------- legacy (R9) kernel: fallback when ws too small ----------------
__global__ __launch_bounds__(256, 3)
void attn_fwd_legacy(const float* __restrict__ Q, const float* __restrict__ K,
                     const float* __restrict__ V, float* __restrict__ O) {
    __shared__ __align__(16) _Float16 K_lds[KVBLK * KPAD];
    __shared__ __align__(16) _Float16 V_lds[KVBLK * DHEAD];
    __shared__ __align__(16) _Float16 P_lds[4 * 16 * PPAD];

    const int tid  = threadIdx.x;
    const int lane = tid & 63;
    const int wave = tid >> 6;
    const int g    = lane >> 4;
    const int lg   = lane & 15;

    const int flat    = blockIdx.x + gridDim.x * blockIdx.y;   // 0..2047
    const int newflat = (flat & 7) * 256 + (flat >> 3);
    const int qtile   = newflat & 31;
    const int bh      = newflat >> 5;

    const size_t base = (size_t)bh * SEQ * DHEAD;
    const float* Qg = Q + base + (size_t)(qtile * 64) * DHEAD;
    const float* Kg = K + base;
    const float* Vg = V + base;
    float*       Og = O + base + (size_t)(qtile * 64) * DHEAD;

    const unsigned trbase = (unsigned)(size_t)&V_lds[0] + (unsigned)(g * 2048 + lg * 8);

    f16x8 qf[4];
    {
        const float* qrow = Qg + (size_t)(wave * 16 + lg) * DHEAD;
        #pragma unroll
        for (int dc = 0; dc < 4; ++dc) {
            const int d0 = dc * 32 + g * 8;
            float4 f0 = *(const float4*)(qrow + d0);
            float4 f1 = *(const float4*)(qrow + d0 + 4);
            qf[dc][0] = (_Float16)f0.x; qf[dc][1] = (_Float16)f0.y;
            qf[dc][2] = (_Float16)f0.z; qf[dc][3] = (_Float16)f0.w;
            qf[dc][4] = (_Float16)f1.x; qf[dc][5] = (_Float16)f1.y;
            qf[dc][6] = (_Float16)f1.z; qf[dc][7] = (_Float16)f1.w;
        }
    }

    f32x4 acc[8];
    #pragma unroll
    for (int dt = 0; dt < 8; ++dt) { acc[dt][0]=0.f; acc[dt][1]=0.f; acc[dt][2]=0.f; acc[dt][3]=0.f; }
    float m = -1e30f, l = 0.f;

    for (int t = 0; t < NT; ++t) {
        {
            const float* Kt = Kg + (size_t)t * KVBLK * DHEAD;
            #pragma unroll
            for (int j = 0; j < 4; ++j) {
                const int c   = tid + 256 * j;
                const int row = c >> 4;
                const int dc  = (c & 15) * 8;
                float4 f0 = *(const float4*)(Kt + row * DHEAD + dc);
                float4 f1 = *(const float4*)(Kt + row * DHEAD + dc + 4);
                f16x8 vh;
                vh[0]=(_Float16)f0.x; vh[1]=(_Float16)f0.y; vh[2]=(_Float16)f0.z; vh[3]=(_Float16)f0.w;
                vh[4]=(_Float16)f1.x; vh[5]=(_Float16)f1.y; vh[6]=(_Float16)f1.z; vh[7]=(_Float16)f1.w;
                *(f16x8*)&K_lds[row * KPAD + dc] = vh;
            }
            const float* Vt = Vg + (size_t)t * KVBLK * DHEAD;
            #pragma unroll
            for (int j = 0; j < 4; ++j) {
                const int c   = tid + 256 * j;
                const int d8  = (c & 1) | (((c >> 3) & 7) << 1);
                const int row = ((c >> 1) & 3) | ((c >> 6) << 2);
                const int d0  = d8 * 8;
                float4 f0 = *(const float4*)(Vt + row * DHEAD + d0);
                float4 f1 = *(const float4*)(Vt + row * DHEAD + d0 + 4);
                f16x8 vv;
                vv[0]=(_Float16)f0.x; vv[1]=(_Float16)f0.y; vv[2]=(_Float16)f0.z; vv[3]=(_Float16)f0.w;
                vv[4]=(_Float16)f1.x; vv[5]=(_Float16)f1.y; vv[6]=(_Float16)f1.z; vv[7]=(_Float16)f1.w;
                const int st = (row >> 2) * 8 + (d0 >> 4);
                *(f16x8*)&V_lds[st * 64 + (row & 3) * 16 + (d0 & 15)] = vv;
            }
        }
        __syncthreads();

        f32x4 s[4];
        __builtin_amdgcn_s_setprio(1);
        #pragma unroll
        for (int ct = 0; ct < 4; ++ct) {
            f32x4 a; a[0]=0.f; a[1]=0.f; a[2]=0.f; a[3]=0.f;
            #pragma unroll
            for (int dc = 0; dc < 4; ++dc) {
                const int off = (ct * 16 + lg) * KPAD + dc * 32 + g * 8;
                f16x8 kh = *(const f16x8*)&K_lds[off];
                a = __builtin_amdgcn_mfma_f32_16x16x32_f16(kh, qf[dc], a, 0, 0, 0);
            }
            s[ct] = a;
        }
        __builtin_amdgcn_s_setprio(0);

        float pmax = s[0][0];
        #pragma unroll
        for (int ct = 0; ct < 4; ++ct)
            #pragma unroll
            for (int r = 0; r < 4; ++r)
                pmax = fmaxf(pmax, s[ct][r]);
        pmax = fmaxf(pmax, __shfl_xor(pmax, 16));
        pmax = fmaxf(pmax, __shfl_xor(pmax, 32));
        const float mnew = fmaxf(m, pmax);
        const float sc   = __expf(m - mnew);
        m = mnew;
        float rs = 0.f;
        #pragma unroll
        for (int ct = 0; ct < 4; ++ct)
            #pragma unroll
            for (int r = 0; r < 4; ++r) {
                float p = __expf(s[ct][r] - mnew);
                s[ct][r] = p;
                rs += p;
            }
        rs += __shfl_xor(rs, 16);
        rs += __shfl_xor(rs, 32);
        l = l * sc + rs;

        #pragma unroll
        for (int r = 0; r < 4; ++r) {
            const float scr = __shfl(sc, g * 20 + r);
            #pragma unroll
            for (int dt = 0; dt < 8; ++dt) acc[dt][r] *= scr;
        }

        _Float16* pbase = &P_lds[wave * 16 * PPAD];
        #pragma unroll
        for (int ct = 0; ct < 4; ++ct) {
            f16x4 pk;
            pk[0] = (_Float16)s[ct][0]; pk[1] = (_Float16)s[ct][1];
            pk[2] = (_Float16)s[ct][2]; pk[3] = (_Float16)s[ct][3];
            *(f16x4*)&pbase[lg * PPAD + ct * 16 + g * 4] = pk;
        }

        #pragma unroll
        for (int kt = 0; kt < 2; ++kt) {
            f16x8 pf = *(const f16x8*)&pbase[lg * PPAD + kt * 32 + g * 8];
            #pragma unroll
            for (int dp = 0; dp < 4; ++dp) {
                f16x4 a0, a1, b0, b1;
                asm volatile(
                    "ds_read_b64_tr_b16 %0, %4 offset:%5\n\t"
                    "ds_read_b64_tr_b16 %1, %4 offset:%6\n\t"
                    "ds_read_b64_tr_b16 %2, %4 offset:%7\n\t"
                    "ds_read_b64_tr_b16 %3, %4 offset:%8\n\t"
                    "s_waitcnt lgkmcnt(0)"
                    : "=&v"(a0), "=&v"(a1), "=&v"(b0), "=&v"(b1)
                    : "v"(trbase),
                      "i"(kt * 8192 + (dp * 2 + 0) * 128),
                      "i"(kt * 8192 + 1024 + (dp * 2 + 0) * 128),
                      "i"(kt * 8192 + (dp * 2 + 1) * 128),
                      "i"(kt * 8192 + 1024 + (dp * 2 + 1) * 128)
                    : "memory");
                __builtin_amdgcn_sched_barrier(0);
                f16x8 vf0 = __builtin_shufflevector(a0, a1, 0, 1, 2, 3, 4, 5, 6, 7);
                f16x8 vf1 = __builtin_shufflevector(b0, b1, 0, 1, 2, 3, 4, 5, 6, 7);
                __builtin_amdgcn_s_setprio(1);
                acc[dp * 2 + 0] = __builtin_amdgcn_mfma_f32_16x16x32_f16(pf, vf0, acc[dp * 2 + 0], 0, 0, 0);
                acc[dp * 2 + 1] = __builtin_amdgcn_mfma_f32_16x16x32_f16(pf, vf1, acc[dp * 2 + 1], 0, 0, 0);
                __builtin_amdgcn_s_setprio(0);
            }
        }
        __syncthreads();
    }

    const float linv = 1.f / l;
    float inv[4];
    #pragma unroll
    for (int r = 0; r < 4; ++r) inv[r] = __shfl(linv, g * 20 + r);
    float* ob = Og + (size_t)(wave * 16) * DHEAD;
    #pragma unroll
    for (int dt = 0; dt < 8; ++dt)
        #pragma unroll
        for (int r = 0; r < 4; ++r)
            ob[(size_t)(g * 4 + r) * DHEAD + dt * 16 + lg] = acc[dt][r] * inv[r];
}

extern "C" void kernel_launch(void* const* d_in, const int* in_sizes, int n_in,
                              void* d_out, int out_size, void* d_ws, size_t ws_size,
                              hipStream_t stream) {
    const float* q = (const float*)d_in[0];
    const float* k = (const float*)d_in[1];
    const float* v = (const float*)d_in[2];
    float* out = (float*)d_out;
    const int BH = in_sizes[0] / (SEQ * DHEAD);   // 64

    const size_t elems = (size_t)BH * SEQ * DHEAD;           // 16M
    const size_t need  = elems * 2 * sizeof(_Float16);       // 64 MB
    if (ws_size >= need) {
        _Float16* Kp = (_Float16*)d_ws;
        _Float16* Vp = Kp + elems;
        preconv_kernel<<<dim3(BH * (SEQ / KVBLK)), dim3(256), 0, stream>>>(k, v, Kp, Vp);
        attn_fwd_kernel<<<dim3(SEQ / QBLK, BH), dim3(512), 0, stream>>>(q, Kp, Vp, out);
    } else {
        attn_fwd_legacy<<<dim3(SEQ / 64, BH), dim3(256), 0, stream>>>(q, k, v, out);
    }
}

// Round 18
// 213.511 us; speedup vs baseline: 1.5909x; 1.0416x over previous
//
#include <hip/hip_runtime.h>
#include <hip/hip_bf16.h>

// Flash-attention forward, B=4 H=16 S=2048 D=128, fp32 in/out, no 1/sqrt(D) scale.
// Round 17: fix R16 — remove permlane32_swap (unverified HW convention was the
//   failure suspect). P is now consumed ENTIRELY lane-locally: the PV k-bijection
//   is chosen to equal the C/D row layout (delta(l5,i)=4*l5+(i&3)+8*(i>>2)), and
//   the pre-pass permutes each V^T granule's content to match. Zero shuffles,
//   zero LDS for P. Everything else = R16 (32x32x16 MFMA, 4-wave blocks, K/V dbuf,
//   defer-max, XCD-gather, gload_lds staging, setprio).

#define KVBLK  64
#define DHEAD  128
#define SEQ    2048
#define NT     (SEQ / KVBLK)
#define KPAD   136   // legacy kernel only
#define PPAD   72    // legacy kernel only
#define RESCALE_THR 8.0f

typedef _Float16 f16x8 __attribute__((ext_vector_type(8)));
typedef _Float16 f16x4 __attribute__((ext_vector_type(4)));
typedef float    f32x4  __attribute__((ext_vector_type(4)));
typedef float    f32x16 __attribute__((ext_vector_type(16)));

#define AS1P(x) ((const __attribute__((address_space(1))) void*)(size_t)(x))
#define AS3P(x) ((__attribute__((address_space(3))) void*)(unsigned long long)(unsigned)(size_t)(x))

// ---------------- pre-pass: fp32 -> fp16, LDS-linear tile layouts ----------------
__global__ __launch_bounds__(256)
void preconv_kernel(const float* __restrict__ K, const float* __restrict__ V,
                    _Float16* __restrict__ Kp, _Float16* __restrict__ Vp) {
    const int bt = blockIdx.x;                       // bh*32 + t (tiles contiguous)
    const size_t src = (size_t)bt * (KVBLK * DHEAD);
    const float* Kt = K + src;
    const float* Vt = V + src;
    _Float16* Ko = Kp + src;
    _Float16* Vo = Vp + src;
    #pragma unroll
    for (int j = 0; j < 4; ++j) {
        const int c = threadIdx.x + 256 * j;         // 0..1023
        // K: row-major [kv][d], 8-elem granule XOR by (kv&7)
        {
            const int row = c >> 4;
            const int d0  = (c & 15) * 8;
            float4 f0 = *(const float4*)(Kt + row * DHEAD + d0);
            float4 f1 = *(const float4*)(Kt + row * DHEAD + d0 + 4);
            f16x8 h;
            h[0]=(_Float16)f0.x; h[1]=(_Float16)f0.y; h[2]=(_Float16)f0.z; h[3]=(_Float16)f0.w;
            h[4]=(_Float16)f1.x; h[5]=(_Float16)f1.y; h[6]=(_Float16)f1.z; h[7]=(_Float16)f1.w;
            *(f16x8*)&Ko[row * 128 + (d0 ^ ((row & 7) << 3))] = h;
        }
        // V^T: [d][kv], granule G=2*kt+h holds kv = 16kt+4h+{0..3} then 16kt+8+4h+{0..3}
        //      (content permuted so pa can be built lane-locally from C/D registers);
        //      granule index XOR-swizzled by (d&7) as before.
        {
            const int d  = c & 127;                  // coalesced across lanes per i
            const int G  = c >> 7;                   // 0..7
            const int kt = G >> 1, hh = G & 1;
            f16x8 h;
            #pragma unroll
            for (int i = 0; i < 8; ++i) {
                const int kv = kt * 16 + 4 * hh + (i & 3) + 8 * (i >> 2);
                h[i] = (_Float16)Vt[kv * DHEAD + d];
            }
            *(f16x8*)&Vo[d * 64 + (G ^ (d & 7)) * 8] = h;
        }
    }
}

// ---------------- main kernel: 4 waves x 32 q-rows, 32x32x16 MFMA ----------------
__global__ __launch_bounds__(256, 2)
void attn_fwd_kernel32(const float* __restrict__ Q, const _Float16* __restrict__ Kp,
                       const _Float16* __restrict__ Vp, float* __restrict__ O) {
    __shared__ __align__(16) _Float16 K_lds[2][KVBLK * DHEAD];   // [kv][d] swz
    __shared__ __align__(16) _Float16 V_lds[2][KVBLK * DHEAD];   // [d][kv] swz (permuted granules)

    const int tid  = threadIdx.x;
    const int lane = tid & 63;
    const int wave = tid >> 6;          // 0..3
    const int l31  = lane & 31;
    const int l5   = lane >> 5;

    // XCD-gather swizzle (1024 blocks = 8 * 128)
    const int flat    = blockIdx.x + gridDim.x * blockIdx.y;
    const int newflat = (flat & 7) * 128 + (flat >> 3);
    const int qtile   = newflat & 15;   // 16 q-tiles of 128 rows
    const int bh      = newflat >> 4;

    const float* Qg = Q + (size_t)bh * SEQ * DHEAD + (size_t)(qtile * 128) * DHEAD;
    float*       Og = O + (size_t)bh * SEQ * DHEAD + (size_t)(qtile * 128) * DHEAD;

    // ---- Q fragments (fp16), B-operand layout: col=q=lane&31, k=dc*16+l5*8+i
    f16x8 qf[8];
    {
        const float* qrow = Qg + (size_t)(wave * 32 + l31) * DHEAD;
        #pragma unroll
        for (int dc = 0; dc < 8; ++dc) {
            const int d0 = dc * 16 + l5 * 8;
            float4 f0 = *(const float4*)(qrow + d0);
            float4 f1 = *(const float4*)(qrow + d0 + 4);
            qf[dc][0] = (_Float16)f0.x; qf[dc][1] = (_Float16)f0.y;
            qf[dc][2] = (_Float16)f0.z; qf[dc][3] = (_Float16)f0.w;
            qf[dc][4] = (_Float16)f1.x; qf[dc][5] = (_Float16)f1.y;
            qf[dc][6] = (_Float16)f1.z; qf[dc][7] = (_Float16)f1.w;
        }
    }

    f32x16 acc[4];
    #pragma unroll
    for (int dt = 0; dt < 4; ++dt)
        #pragma unroll
        for (int r = 0; r < 16; ++r) acc[dt][r] = 0.f;
    float m = -1e30f, l = 0.f;

    #define STAGE(B, T) {                                                          \
        const _Float16* Ktile = Kp + (size_t)(bh * 32 + (T)) * (KVBLK * DHEAD);    \
        const _Float16* Vtile = Vp + (size_t)(bh * 32 + (T)) * (KVBLK * DHEAD);    \
        _Pragma("unroll")                                                          \
        for (int i = 0; i < 4; ++i) {                                              \
            const int eoff = wave * 2048 + i * 512;                                \
            __builtin_amdgcn_global_load_lds(AS1P(Ktile + eoff + lane * 8),        \
                                             AS3P(&K_lds[B][eoff]), 16, 0, 0);     \
            __builtin_amdgcn_global_load_lds(AS1P(Vtile + eoff + lane * 8),        \
                                             AS3P(&V_lds[B][eoff]), 16, 0, 0);     \
        }                                                                          \
    }

    #define COMPUTE(B) {                                                           \
        f32x16 s[2];                                                               \
        __builtin_amdgcn_s_setprio(1);                                             \
        _Pragma("unroll")                                                          \
        for (int ct = 0; ct < 2; ++ct) {                                           \
            f32x16 a;                                                              \
            _Pragma("unroll")                                                      \
            for (int r = 0; r < 16; ++r) a[r] = 0.f;                               \
            _Pragma("unroll")                                                      \
            for (int dc = 0; dc < 8; ++dc) {                                       \
                const int kv = ct * 32 + l31;                                      \
                const int koff = kv * 128 + (((dc * 2 + l5) ^ (kv & 7)) * 8);      \
                f16x8 kh = *(const f16x8*)&K_lds[B][koff];                         \
                a = __builtin_amdgcn_mfma_f32_32x32x16_f16(kh, qf[dc], a, 0, 0, 0);\
            }                                                                      \
            s[ct] = a;                                                             \
        }                                                                          \
        __builtin_amdgcn_s_setprio(0);                                             \
        float pmax = s[0][0];                                                      \
        _Pragma("unroll")                                                          \
        for (int ct = 0; ct < 2; ++ct)                                             \
            _Pragma("unroll")                                                      \
            for (int r = 0; r < 16; ++r)                                           \
                pmax = fmaxf(pmax, s[ct][r]);                                      \
        pmax = fmaxf(pmax, __shfl_xor(pmax, 32));                                  \
        if (!__all(pmax - m <= RESCALE_THR)) {                                     \
            const float mnew = fmaxf(m, pmax);                                     \
            const float sc   = __expf(m - mnew);                                   \
            m = mnew;                                                              \
            l *= sc;                                                               \
            _Pragma("unroll")                                                      \
            for (int r = 0; r < 16; ++r) {                                         \
                const float scr = __shfl(sc, (r & 3) + 8 * (r >> 2) + 4 * l5);     \
                _Pragma("unroll")                                                  \
                for (int dt = 0; dt < 4; ++dt) acc[dt][r] *= scr;                  \
            }                                                                      \
        }                                                                          \
        float rs = 0.f;                                                            \
        _Pragma("unroll")                                                          \
        for (int ct = 0; ct < 2; ++ct)                                             \
            _Pragma("unroll")                                                      \
            for (int r = 0; r < 16; ++r) {                                         \
                float p = __expf(s[ct][r] - m);                                    \
                s[ct][r] = p;                                                      \
                rs += p;                                                           \
            }                                                                      \
        rs += __shfl_xor(rs, 32);                                                  \
        l += rs;                                                                   \
        /* P -> A-frags, LANE-LOCAL: pa[kt][i] = P[q][kt*16 + 4*l5 + (i&3) + 8*(i>>2)]  \
           = s[kt>>1][4*(2*(kt&1)+(i>>2)) + (i&3)]  (matches permuted V^T granules) */  \
        f16x8 pa[4];                                                               \
        _Pragma("unroll")                                                          \
        for (int kt = 0; kt < 4; ++kt)                                             \
            _Pragma("unroll")                                                      \
            for (int i = 0; i < 8; ++i)                                            \
                pa[kt][i] = (_Float16)s[kt >> 1][4 * (2 * (kt & 1) + (i >> 2)) + (i & 3)]; \
        /* PV */                                                                   \
        __builtin_amdgcn_s_setprio(1);                                             \
        _Pragma("unroll")                                                          \
        for (int kt = 0; kt < 4; ++kt)                                             \
            _Pragma("unroll")                                                      \
            for (int dt = 0; dt < 4; ++dt) {                                       \
                const int d = dt * 32 + l31;                                       \
                const int voff = d * 64 + (((kt * 2 + l5) ^ (d & 7)) * 8);         \
                f16x8 vf = *(const f16x8*)&V_lds[B][voff];                         \
                acc[dt] = __builtin_amdgcn_mfma_f32_32x32x16_f16(pa[kt], vf, acc[dt], 0, 0, 0); \
            }                                                                      \
        __builtin_amdgcn_s_setprio(0);                                             \
    }

    // prologue
    STAGE(0, 0);
    __syncthreads();

    #pragma unroll 1
    for (int tt = 0; tt < NT / 2; ++tt) {
        const int t0 = tt * 2;
        STAGE(1, t0 + 1);
        COMPUTE(0);
        __syncthreads();
        if (t0 + 2 < NT) STAGE(0, t0 + 2);
        COMPUTE(1);
        __syncthreads();
    }

    #undef STAGE
    #undef COMPUTE

    // ---- epilogue: O[q][d] = acc / l ; q-row of reg r = (r&3)+8*(r>>2)+4*l5
    const float linv = 1.f / l;
    float inv[16];
    #pragma unroll
    for (int r = 0; r < 16; ++r) inv[r] = __shfl(linv, (r & 3) + 8 * (r >> 2) + 4 * l5);
    #pragma unroll
    for (int dt = 0; dt < 4; ++dt)
        #pragma unroll
        for (int r = 0; r < 16; ++r) {
            const int qrow = wave * 32 + (r & 3) + 8 * (r >> 2) + 4 * l5;
            Og[(size_t)qrow * DHEAD + dt * 32 + l31] = acc[dt][r] * inv[r];
        }
}

// ---------------- legacy (R9) kernel: fallback when ws too small ----------------
__global__ __launch_bounds__(256, 3)
void attn_fwd_legacy(const float* __restrict__ Q, const float* __restrict__ K,
                     const float* __restrict__ V, float* __restrict__ O) {
    __shared__ __align__(16) _Float16 K_lds[KVBLK * KPAD];
    __shared__ __align__(16) _Float16 V_lds[KVBLK * DHEAD];
    __shared__ __align__(16) _Float16 P_lds[4 * 16 * PPAD];

    const int tid  = threadIdx.x;
    const int lane = tid & 63;
    const int wave = tid >> 6;
    const int g    = lane >> 4;
    const int lg   = lane & 15;

    const int flat    = blockIdx.x + gridDim.x * blockIdx.y;   // 0..2047
    const int newflat = (flat & 7) * 256 + (flat >> 3);
    const int qtile   = newflat & 31;
    const int bh      = newflat >> 5;

    const size_t base = (size_t)bh * SEQ * DHEAD;
    const float* Qg = Q + base + (size_t)(qtile * 64) * DHEAD;
    const float* Kg = K + base;
    const float* Vg = V + base;
    float*       Og = O + base + (size_t)(qtile * 64) * DHEAD;

    const unsigned trbase = (unsigned)(size_t)&V_lds[0] + (unsigned)(g * 2048 + lg * 8);

    f16x8 qf[4];
    {
        const float* qrow = Qg + (size_t)(wave * 16 + lg) * DHEAD;
        #pragma unroll
        for (int dc = 0; dc < 4; ++dc) {
            const int d0 = dc * 32 + g * 8;
            float4 f0 = *(const float4*)(qrow + d0);
            float4 f1 = *(const float4*)(qrow + d0 + 4);
            qf[dc][0] = (_Float16)f0.x; qf[dc][1] = (_Float16)f0.y;
            qf[dc][2] = (_Float16)f0.z; qf[dc][3] = (_Float16)f0.w;
            qf[dc][4] = (_Float16)f1.x; qf[dc][5] = (_Float16)f1.y;
            qf[dc][6] = (_Float16)f1.z; qf[dc][7] = (_Float16)f1.w;
        }
    }

    f32x4 acc[8];
    #pragma unroll
    for (int dt = 0; dt < 8; ++dt) { acc[dt][0]=0.f; acc[dt][1]=0.f; acc[dt][2]=0.f; acc[dt][3]=0.f; }
    float m = -1e30f, l = 0.f;

    for (int t = 0; t < NT; ++t) {
        {
            const float* Kt = Kg + (size_t)t * KVBLK * DHEAD;
            #pragma unroll
            for (int j = 0; j < 4; ++j) {
                const int c   = tid + 256 * j;
                const int row = c >> 4;
                const int dc  = (c & 15) * 8;
                float4 f0 = *(const float4*)(Kt + row * DHEAD + dc);
                float4 f1 = *(const float4*)(Kt + row * DHEAD + dc + 4);
                f16x8 vh;
                vh[0]=(_Float16)f0.x; vh[1]=(_Float16)f0.y; vh[2]=(_Float16)f0.z; vh[3]=(_Float16)f0.w;
                vh[4]=(_Float16)f1.x; vh[5]=(_Float16)f1.y; vh[6]=(_Float16)f1.z; vh[7]=(_Float16)f1.w;
                *(f16x8*)&K_lds[row * KPAD + dc] = vh;
            }
            const float* Vt = Vg + (size_t)t * KVBLK * DHEAD;
            #pragma unroll
            for (int j = 0; j < 4; ++j) {
                const int c   = tid + 256 * j;
                const int d8  = (c & 1) | (((c >> 3) & 7) << 1);
                const int row = ((c >> 1) & 3) | ((c >> 6) << 2);
                const int d0  = d8 * 8;
                float4 f0 = *(const float4*)(Vt + row * DHEAD + d0);
                float4 f1 = *(const float4*)(Vt + row * DHEAD + d0 + 4);
                f16x8 vv;
                vv[0]=(_Float16)f0.x; vv[1]=(_Float16)f0.y; vv[2]=(_Float16)f0.z; vv[3]=(_Float16)f0.w;
                vv[4]=(_Float16)f1.x; vv[5]=(_Float16)f1.y; vv[6]=(_Float16)f1.z; vv[7]=(_Float16)f1.w;
                const int st = (row >> 2) * 8 + (d0 >> 4);
                *(f16x8*)&V_lds[st * 64 + (row & 3) * 16 + (d0 & 15)] = vv;
            }
        }
        __syncthreads();

        f32x4 s[4];
        __builtin_amdgcn_s_setprio(1);
        #pragma unroll
        for (int ct = 0; ct < 4; ++ct) {
            f32x4 a; a[0]=0.f; a[1]=0.f; a[2]=0.f; a[3]=0.f;
            #pragma unroll
            for (int dc = 0; dc < 4; ++dc) {
                const int off = (ct * 16 + lg) * KPAD + dc * 32 + g * 8;
                f16x8 kh = *(const f16x8*)&K_lds[off];
                a = __builtin_amdgcn_mfma_f32_16x16x32_f16(kh, qf[dc], a, 0, 0, 0);
            }
            s[ct] = a;
        }
        __builtin_amdgcn_s_setprio(0);

        float pmax = s[0][0];
        #pragma unroll
        for (int ct = 0; ct < 4; ++ct)
            #pragma unroll
            for (int r = 0; r < 4; ++r)
                pmax = fmaxf(pmax, s[ct][r]);
        pmax = fmaxf(pmax, __shfl_xor(pmax, 16));
        pmax = fmaxf(pmax, __shfl_xor(pmax, 32));
        const float mnew = fmaxf(m, pmax);
        const float sc   = __expf(m - mnew);
        m = mnew;
        float rs = 0.f;
        #pragma unroll
        for (int ct = 0; ct < 4; ++ct)
            #pragma unroll
            for (int r = 0; r < 4; ++r) {
                float p = __expf(s[ct][r] - mnew);
                s[ct][r] = p;
                rs += p;
            }
        rs += __shfl_xor(rs, 16);
        rs += __shfl_xor(rs, 32);
        l = l * sc + rs;

        #pragma unroll
        for (int r = 0; r < 4; ++r) {
            const float scr = __shfl(sc, g * 20 + r);
            #pragma unroll
            for (int dt = 0; dt < 8; ++dt) acc[dt][r] *= scr;
        }

        _Float16* pbase = &P_lds[wave * 16 * PPAD];
        #pragma unroll
        for (int ct = 0; ct < 4; ++ct) {
            f16x4 pk;
            pk[0] = (_Float16)s[ct][0]; pk[1] = (_Float16)s[ct][1];
            pk[2] = (_Float16)s[ct][2]; pk[3] = (_Float16)s[ct][3];
            *(f16x4*)&pbase[lg * PPAD + ct * 16 + g * 4] = pk;
        }

        #pragma unroll
        for (int kt = 0; kt < 2; ++kt) {
            f16x8 pf = *(const f16x8*)&pbase[lg * PPAD + kt * 32 + g * 8];
            #pragma unroll
            for (int dp = 0; dp < 4; ++dp) {
                f16x4 a0, a1, b0, b1;
                asm volatile(
                    "ds_read_b64_tr_b16 %0, %4 offset:%5\n\t"
                    "ds_read_b64_tr_b16 %1, %4 offset:%6\n\t"
                    "ds_read_b64_tr_b16 %2, %4 offset:%7\n\t"
                    "ds_read_b64_tr_b16 %3, %4 offset:%8\n\t"
                    "s_waitcnt lgkmcnt(0)"
                    : "=&v"(a0), "=&v"(a1), "=&v"(b0), "=&v"(b1)
                    : "v"(trbase),
                      "i"(kt * 8192 + (dp * 2 + 0) * 128),
                      "i"(kt * 8192 + 1024 + (dp * 2 + 0) * 128),
                      "i"(kt * 8192 + (dp * 2 + 1) * 128),
                      "i"(kt * 8192 + 1024 + (dp * 2 + 1) * 128)
                    : "memory");
                __builtin_amdgcn_sched_barrier(0);
                f16x8 vf0 = __builtin_shufflevector(a0, a1, 0, 1, 2, 3, 4, 5, 6, 7);
                f16x8 vf1 = __builtin_shufflevector(b0, b1, 0, 1, 2, 3, 4, 5, 6, 7);
                __builtin_amdgcn_s_setprio(1);
                acc[dp * 2 + 0] = __builtin_amdgcn_mfma_f32_16x16x32_f16(pf, vf0, acc[dp * 2 + 0], 0, 0, 0);
                acc[dp * 2 + 1] = __builtin_amdgcn_mfma_f32_16x16x32_f16(pf, vf1, acc[dp * 2 + 1], 0, 0, 0);
                __builtin_amdgcn_s_setprio(0);
            }
        }
        __syncthreads();
    }

    const float linv = 1.f / l;
    float inv[4];
    #pragma unroll
    for (int r = 0; r < 4; ++r) inv[r] = __shfl(linv, g * 20 + r);
    float* ob = Og + (size_t)(wave * 16) * DHEAD;
    #pragma unroll
    for (int dt = 0; dt < 8; ++dt)
        #pragma unroll
        for (int r = 0; r < 4; ++r)
            ob[(size_t)(g * 4 + r) * DHEAD + dt * 16 + lg] = acc[dt][r] * inv[r];
}

extern "C" void kernel_launch(void* const* d_in, const int* in_sizes, int n_in,
                              void* d_out, int out_size, void* d_ws, size_t ws_size,
                              hipStream_t stream) {
    const float* q = (const float*)d_in[0];
    const float* k = (const float*)d_in[1];
    const float* v = (const float*)d_in[2];
    float* out = (float*)d_out;
    const int BH = in_sizes[0] / (SEQ * DHEAD);   // 64

    const size_t elems = (size_t)BH * SEQ * DHEAD;           // 16M
    const size_t need  = elems * 2 * sizeof(_Float16);       // 64 MB
    if (ws_size >= need) {
        _Float16* Kp = (_Float16*)d_ws;
        _Float16* Vp = Kp + elems;
        preconv_kernel<<<dim3(BH * (SEQ / KVBLK)), dim3(256), 0, stream>>>(k, v, Kp, Vp);
        attn_fwd_kernel32<<<dim3(SEQ / 128, BH), dim3(256), 0, stream>>>(q, Kp, Vp, out);
    } else {
        attn_fwd_legacy<<<dim3(SEQ / 64, BH), dim3(256), 0, stream>>>(q, k, v, out);
    }
}

// Round 19
// 211.609 us; speedup vs baseline: 1.6052x; 1.0090x over previous
//
#include <hip/hip_runtime.h>
#include <hip/hip_bf16.h>

// Flash-attention forward, B=4 H=16 S=2048 D=128, fp32 in/out, no 1/sqrt(D) scale.
// Round 18: occupancy recovery — 512-thread (8-wave) blocks sharing the same 64KB
//   K/V double-buffer; per-wave structure identical to R17 (32 q-rows, 32x32x16
//   MFMA, lane-local P, defer-max). 2 blocks/CU -> 16 waves/CU (was 8).
//   Keeps: pre-pass (K swz / permuted V^T swz), gload_lds staging, XCD-gather,
//   1-barrier/tile dbuf schedule, setprio.

#define KVBLK  64
#define DHEAD  128
#define SEQ    2048
#define NT     (SEQ / KVBLK)
#define KPAD   136   // legacy kernel only
#define PPAD   72    // legacy kernel only
#define RESCALE_THR 8.0f

typedef _Float16 f16x8 __attribute__((ext_vector_type(8)));
typedef _Float16 f16x4 __attribute__((ext_vector_type(4)));
typedef float    f32x4  __attribute__((ext_vector_type(4)));
typedef float    f32x16 __attribute__((ext_vector_type(16)));

#define AS1P(x) ((const __attribute__((address_space(1))) void*)(size_t)(x))
#define AS3P(x) ((__attribute__((address_space(3))) void*)(unsigned long long)(unsigned)(size_t)(x))

// ---------------- pre-pass: fp32 -> fp16, LDS-linear tile layouts ----------------
__global__ __launch_bounds__(256)
void preconv_kernel(const float* __restrict__ K, const float* __restrict__ V,
                    _Float16* __restrict__ Kp, _Float16* __restrict__ Vp) {
    const int bt = blockIdx.x;                       // bh*32 + t (tiles contiguous)
    const size_t src = (size_t)bt * (KVBLK * DHEAD);
    const float* Kt = K + src;
    const float* Vt = V + src;
    _Float16* Ko = Kp + src;
    _Float16* Vo = Vp + src;
    #pragma unroll
    for (int j = 0; j < 4; ++j) {
        const int c = threadIdx.x + 256 * j;         // 0..1023
        // K: row-major [kv][d], 8-elem granule XOR by (kv&7)
        {
            const int row = c >> 4;
            const int d0  = (c & 15) * 8;
            float4 f0 = *(const float4*)(Kt + row * DHEAD + d0);
            float4 f1 = *(const float4*)(Kt + row * DHEAD + d0 + 4);
            f16x8 h;
            h[0]=(_Float16)f0.x; h[1]=(_Float16)f0.y; h[2]=(_Float16)f0.z; h[3]=(_Float16)f0.w;
            h[4]=(_Float16)f1.x; h[5]=(_Float16)f1.y; h[6]=(_Float16)f1.z; h[7]=(_Float16)f1.w;
            *(f16x8*)&Ko[row * 128 + (d0 ^ ((row & 7) << 3))] = h;
        }
        // V^T: [d][kv], granule G=2*kt+h holds kv = 16kt+4h+{0..3} then 16kt+8+4h+{0..3}
        //      (content permuted so pa is built lane-locally from C/D registers);
        //      granule index XOR-swizzled by (d&7).
        {
            const int d  = c & 127;                  // coalesced across lanes per i
            const int G  = c >> 7;                   // 0..7
            const int kt = G >> 1, hh = G & 1;
            f16x8 h;
            #pragma unroll
            for (int i = 0; i < 8; ++i) {
                const int kv = kt * 16 + 4 * hh + (i & 3) + 8 * (i >> 2);
                h[i] = (_Float16)Vt[kv * DHEAD + d];
            }
            *(f16x8*)&Vo[d * 64 + (G ^ (d & 7)) * 8] = h;
        }
    }
}

// ---------------- main kernel: 8 waves x 32 q-rows, 32x32x16 MFMA ----------------
__global__ __launch_bounds__(512, 2)
void attn_fwd_kernel32(const float* __restrict__ Q, const _Float16* __restrict__ Kp,
                       const _Float16* __restrict__ Vp, float* __restrict__ O) {
    __shared__ __align__(16) _Float16 K_lds[2][KVBLK * DHEAD];   // [kv][d] swz
    __shared__ __align__(16) _Float16 V_lds[2][KVBLK * DHEAD];   // [d][kv] swz (permuted granules)

    const int tid  = threadIdx.x;
    const int lane = tid & 63;
    const int wave = tid >> 6;          // 0..7
    const int l31  = lane & 31;
    const int l5   = lane >> 5;

    // XCD-gather swizzle (512 blocks = 8 * 64)
    const int flat    = blockIdx.x + gridDim.x * blockIdx.y;
    const int newflat = (flat & 7) * 64 + (flat >> 3);
    const int qtile   = newflat & 7;    // 8 q-tiles of 256 rows
    const int bh      = newflat >> 3;

    const float* Qg = Q + (size_t)bh * SEQ * DHEAD + (size_t)(qtile * 256) * DHEAD;
    float*       Og = O + (size_t)bh * SEQ * DHEAD + (size_t)(qtile * 256) * DHEAD;

    // ---- Q fragments (fp16), B-operand layout: col=q=lane&31, k=dc*16+l5*8+i
    f16x8 qf[8];
    {
        const float* qrow = Qg + (size_t)(wave * 32 + l31) * DHEAD;
        #pragma unroll
        for (int dc = 0; dc < 8; ++dc) {
            const int d0 = dc * 16 + l5 * 8;
            float4 f0 = *(const float4*)(qrow + d0);
            float4 f1 = *(const float4*)(qrow + d0 + 4);
            qf[dc][0] = (_Float16)f0.x; qf[dc][1] = (_Float16)f0.y;
            qf[dc][2] = (_Float16)f0.z; qf[dc][3] = (_Float16)f0.w;
            qf[dc][4] = (_Float16)f1.x; qf[dc][5] = (_Float16)f1.y;
            qf[dc][6] = (_Float16)f1.z; qf[dc][7] = (_Float16)f1.w;
        }
    }

    f32x16 acc[4];
    #pragma unroll
    for (int dt = 0; dt < 4; ++dt)
        #pragma unroll
        for (int r = 0; r < 16; ++r) acc[dt][r] = 0.f;
    float m = -1e30f, l = 0.f;

    // 8 waves share each tile: 2 gload_lds calls per wave per buffer (K and V)
    #define STAGE(B, T) {                                                          \
        const _Float16* Ktile = Kp + (size_t)(bh * 32 + (T)) * (KVBLK * DHEAD);    \
        const _Float16* Vtile = Vp + (size_t)(bh * 32 + (T)) * (KVBLK * DHEAD);    \
        _Pragma("unroll")                                                          \
        for (int i = 0; i < 2; ++i) {                                              \
            const int eoff = wave * 1024 + i * 512;                                \
            __builtin_amdgcn_global_load_lds(AS1P(Ktile + eoff + lane * 8),        \
                                             AS3P(&K_lds[B][eoff]), 16, 0, 0);     \
            __builtin_amdgcn_global_load_lds(AS1P(Vtile + eoff + lane * 8),        \
                                             AS3P(&V_lds[B][eoff]), 16, 0, 0);     \
        }                                                                          \
    }

    #define COMPUTE(B) {                                                           \
        f32x16 s[2];                                                               \
        __builtin_amdgcn_s_setprio(1);                                             \
        _Pragma("unroll")                                                          \
        for (int ct = 0; ct < 2; ++ct) {                                           \
            f32x16 a;                                                              \
            _Pragma("unroll")                                                      \
            for (int r = 0; r < 16; ++r) a[r] = 0.f;                               \
            _Pragma("unroll")                                                      \
            for (int dc = 0; dc < 8; ++dc) {                                       \
                const int kv = ct * 32 + l31;                                      \
                const int koff = kv * 128 + (((dc * 2 + l5) ^ (kv & 7)) * 8);      \
                f16x8 kh = *(const f16x8*)&K_lds[B][koff];                         \
                a = __builtin_amdgcn_mfma_f32_32x32x16_f16(kh, qf[dc], a, 0, 0, 0);\
            }                                                                      \
            s[ct] = a;                                                             \
        }                                                                          \
        __builtin_amdgcn_s_setprio(0);                                             \
        float pmax = s[0][0];                                                      \
        _Pragma("unroll")                                                          \
        for (int ct = 0; ct < 2; ++ct)                                             \
            _Pragma("unroll")                                                      \
            for (int r = 0; r < 16; ++r)                                           \
                pmax = fmaxf(pmax, s[ct][r]);                                      \
        pmax = fmaxf(pmax, __shfl_xor(pmax, 32));                                  \
        if (!__all(pmax - m <= RESCALE_THR)) {                                     \
            const float mnew = fmaxf(m, pmax);                                     \
            const float sc   = __expf(m - mnew);                                   \
            m = mnew;                                                              \
            l *= sc;                                                               \
            _Pragma("unroll")                                                      \
            for (int r = 0; r < 16; ++r) {                                         \
                const float scr = __shfl(sc, (r & 3) + 8 * (r >> 2) + 4 * l5);     \
                _Pragma("unroll")                                                  \
                for (int dt = 0; dt < 4; ++dt) acc[dt][r] *= scr;                  \
            }                                                                      \
        }                                                                          \
        float rs = 0.f;                                                            \
        _Pragma("unroll")                                                          \
        for (int ct = 0; ct < 2; ++ct)                                             \
            _Pragma("unroll")                                                      \
            for (int r = 0; r < 16; ++r) {                                         \
                float p = __expf(s[ct][r] - m);                                    \
                s[ct][r] = p;                                                      \
                rs += p;                                                           \
            }                                                                      \
        rs += __shfl_xor(rs, 32);                                                  \
        l += rs;                                                                   \
        /* P -> A-frags, LANE-LOCAL: pa[kt][i] = P[q][kt*16 + 4*l5 + (i&3) + 8*(i>>2)]  \
           = s[kt>>1][4*(2*(kt&1)+(i>>2)) + (i&3)]  (matches permuted V^T granules) */  \
        f16x8 pa[4];                                                               \
        _Pragma("unroll")                                                          \
        for (int kt = 0; kt < 4; ++kt)                                             \
            _Pragma("unroll")                                                      \
            for (int i = 0; i < 8; ++i)                                            \
                pa[kt][i] = (_Float16)s[kt >> 1][4 * (2 * (kt & 1) + (i >> 2)) + (i & 3)]; \
        /* PV */                                                                   \
        __builtin_amdgcn_s_setprio(1);                                             \
        _Pragma("unroll")                                                          \
        for (int kt = 0; kt < 4; ++kt)                                             \
            _Pragma("unroll")                                                      \
            for (int dt = 0; dt < 4; ++dt) {                                       \
                const int d = dt * 32 + l31;                                       \
                const int voff = d * 64 + (((kt * 2 + l5) ^ (d & 7)) * 8);         \
                f16x8 vf = *(const f16x8*)&V_lds[B][voff];                         \
                acc[dt] = __builtin_amdgcn_mfma_f32_32x32x16_f16(pa[kt], vf, acc[dt], 0, 0, 0); \
            }                                                                      \
        __builtin_amdgcn_s_setprio(0);                                             \
    }

    // prologue
    STAGE(0, 0);
    __syncthreads();

    #pragma unroll 1
    for (int tt = 0; tt < NT / 2; ++tt) {
        const int t0 = tt * 2;
        STAGE(1, t0 + 1);
        COMPUTE(0);
        __syncthreads();
        if (t0 + 2 < NT) STAGE(0, t0 + 2);
        COMPUTE(1);
        __syncthreads();
    }

    #undef STAGE
    #undef COMPUTE

    // ---- epilogue: O[q][d] = acc / l ; q-row of reg r = (r&3)+8*(r>>2)+4*l5
    const float linv = 1.f / l;
    float inv[16];
    #pragma unroll
    for (int r = 0; r < 16; ++r) inv[r] = __shfl(linv, (r & 3) + 8 * (r >> 2) + 4 * l5);
    #pragma unroll
    for (int dt = 0; dt < 4; ++dt)
        #pragma unroll
        for (int r = 0; r < 16; ++r) {
            const int qrow = wave * 32 + (r & 3) + 8 * (r >> 2) + 4 * l5;
            Og[(size_t)qrow * DHEAD + dt * 32 + l31] = acc[dt][r] * inv[r];
        }
}

// ---------------- legacy (R9) kernel: fallback when ws too small ----------------
__global__ __launch_bounds__(256, 3)
void attn_fwd_legacy(const float* __restrict__ Q, const float* __restrict__ K,
                     const float* __restrict__ V, float* __restrict__ O) {
    __shared__ __align__(16) _Float16 K_lds[KVBLK * KPAD];
    __shared__ __align__(16) _Float16 V_lds[KVBLK * DHEAD];
    __shared__ __align__(16) _Float16 P_lds[4 * 16 * PPAD];

    const int tid  = threadIdx.x;
    const int lane = tid & 63;
    const int wave = tid >> 6;
    const int g    = lane >> 4;
    const int lg   = lane & 15;

    const int flat    = blockIdx.x + gridDim.x * blockIdx.y;   // 0..2047
    const int newflat = (flat & 7) * 256 + (flat >> 3);
    const int qtile   = newflat & 31;
    const int bh      = newflat >> 5;

    const size_t base = (size_t)bh * SEQ * DHEAD;
    const float* Qg = Q + base + (size_t)(qtile * 64) * DHEAD;
    const float* Kg = K + base;
    const float* Vg = V + base;
    float*       Og = O + base + (size_t)(qtile * 64) * DHEAD;

    const unsigned trbase = (unsigned)(size_t)&V_lds[0] + (unsigned)(g * 2048 + lg * 8);

    f16x8 qf[4];
    {
        const float* qrow = Qg + (size_t)(wave * 16 + lg) * DHEAD;
        #pragma unroll
        for (int dc = 0; dc < 4; ++dc) {
            const int d0 = dc * 32 + g * 8;
            float4 f0 = *(const float4*)(qrow + d0);
            float4 f1 = *(const float4*)(qrow + d0 + 4);
            qf[dc][0] = (_Float16)f0.x; qf[dc][1] = (_Float16)f0.y;
            qf[dc][2] = (_Float16)f0.z; qf[dc][3] = (_Float16)f0.w;
            qf[dc][4] = (_Float16)f1.x; qf[dc][5] = (_Float16)f1.y;
            qf[dc][6] = (_Float16)f1.z; qf[dc][7] = (_Float16)f1.w;
        }
    }

    f32x4 acc[8];
    #pragma unroll
    for (int dt = 0; dt < 8; ++dt) { acc[dt][0]=0.f; acc[dt][1]=0.f; acc[dt][2]=0.f; acc[dt][3]=0.f; }
    float m = -1e30f, l = 0.f;

    for (int t = 0; t < NT; ++t) {
        {
            const float* Kt = Kg + (size_t)t * KVBLK * DHEAD;
            #pragma unroll
            for (int j = 0; j < 4; ++j) {
                const int c   = tid + 256 * j;
                const int row = c >> 4;
                const int dc  = (c & 15) * 8;
                float4 f0 = *(const float4*)(Kt + row * DHEAD + dc);
                float4 f1 = *(const float4*)(Kt + row * DHEAD + dc + 4);
                f16x8 vh;
                vh[0]=(_Float16)f0.x; vh[1]=(_Float16)f0.y; vh[2]=(_Float16)f0.z; vh[3]=(_Float16)f0.w;
                vh[4]=(_Float16)f1.x; vh[5]=(_Float16)f1.y; vh[6]=(_Float16)f1.z; vh[7]=(_Float16)f1.w;
                *(f16x8*)&K_lds[row * KPAD + dc] = vh;
            }
            const float* Vt = Vg + (size_t)t * KVBLK * DHEAD;
            #pragma unroll
            for (int j = 0; j < 4; ++j) {
                const int c   = tid + 256 * j;
                const int d8  = (c & 1) | (((c >> 3) & 7) << 1);
                const int row = ((c >> 1) & 3) | ((c >> 6) << 2);
                const int d0  = d8 * 8;
                float4 f0 = *(const float4*)(Vt + row * DHEAD + d0);
                float4 f1 = *(const float4*)(Vt + row * DHEAD + d0 + 4);
                f16x8 vv;
                vv[0]=(_Float16)f0.x; vv[1]=(_Float16)f0.y; vv[2]=(_Float16)f0.z; vv[3]=(_Float16)f0.w;
                vv[4]=(_Float16)f1.x; vv[5]=(_Float16)f1.y; vv[6]=(_Float16)f1.z; vv[7]=(_Float16)f1.w;
                const int st = (row >> 2) * 8 + (d0 >> 4);
                *(f16x8*)&V_lds[st * 64 + (row & 3) * 16 + (d0 & 15)] = vv;
            }
        }
        __syncthreads();

        f32x4 s[4];
        __builtin_amdgcn_s_setprio(1);
        #pragma unroll
        for (int ct = 0; ct < 4; ++ct) {
            f32x4 a; a[0]=0.f; a[1]=0.f; a[2]=0.f; a[3]=0.f;
            #pragma unroll
            for (int dc = 0; dc < 4; ++dc) {
                const int off = (ct * 16 + lg) * KPAD + dc * 32 + g * 8;
                f16x8 kh = *(const f16x8*)&K_lds[off];
                a = __builtin_amdgcn_mfma_f32_16x16x32_f16(kh, qf[dc], a, 0, 0, 0);
            }
            s[ct] = a;
        }
        __builtin_amdgcn_s_setprio(0);

        float pmax = s[0][0];
        #pragma unroll
        for (int ct = 0; ct < 4; ++ct)
            #pragma unroll
            for (int r = 0; r < 4; ++r)
                pmax = fmaxf(pmax, s[ct][r]);
        pmax = fmaxf(pmax, __shfl_xor(pmax, 16));
        pmax = fmaxf(pmax, __shfl_xor(pmax, 32));
        const float mnew = fmaxf(m, pmax);
        const float sc   = __expf(m - mnew);
        m = mnew;
        float rs = 0.f;
        #pragma unroll
        for (int ct = 0; ct < 4; ++ct)
            #pragma unroll
            for (int r = 0; r < 4; ++r) {
                float p = __expf(s[ct][r] - mnew);
                s[ct][r] = p;
                rs += p;
            }
        rs += __shfl_xor(rs, 16);
        rs += __shfl_xor(rs, 32);
        l = l * sc + rs;

        #pragma unroll
        for (int r = 0; r < 4; ++r) {
            const float scr = __shfl(sc, g * 20 + r);
            #pragma unroll
            for (int dt = 0; dt < 8; ++dt) acc[dt][r] *= scr;
        }

        _Float16* pbase = &P_lds[wave * 16 * PPAD];
        #pragma unroll
        for (int ct = 0; ct < 4; ++ct) {
            f16x4 pk;
            pk[0] = (_Float16)s[ct][0]; pk[1] = (_Float16)s[ct][1];
            pk[2] = (_Float16)s[ct][2]; pk[3] = (_Float16)s[ct][3];
            *(f16x4*)&pbase[lg * PPAD + ct * 16 + g * 4] = pk;
        }

        #pragma unroll
        for (int kt = 0; kt < 2; ++kt) {
            f16x8 pf = *(const f16x8*)&pbase[lg * PPAD + kt * 32 + g * 8];
            #pragma unroll
            for (int dp = 0; dp < 4; ++dp) {
                f16x4 a0, a1, b0, b1;
                asm volatile(
                    "ds_read_b64_tr_b16 %0, %4 offset:%5\n\t"
                    "ds_read_b64_tr_b16 %1, %4 offset:%6\n\t"
                    "ds_read_b64_tr_b16 %2, %4 offset:%7\n\t"
                    "ds_read_b64_tr_b16 %3, %4 offset:%8\n\t"
                    "s_waitcnt lgkmcnt(0)"
                    : "=&v"(a0), "=&v"(a1), "=&v"(b0), "=&v"(b1)
                    : "v"(trbase),
                      "i"(kt * 8192 + (dp * 2 + 0) * 128),
                      "i"(kt * 8192 + 1024 + (dp * 2 + 0) * 128),
                      "i"(kt * 8192 + (dp * 2 + 1) * 128),
                      "i"(kt * 8192 + 1024 + (dp * 2 + 1) * 128)
                    : "memory");
                __builtin_amdgcn_sched_barrier(0);
                f16x8 vf0 = __builtin_shufflevector(a0, a1, 0, 1, 2, 3, 4, 5, 6, 7);
                f16x8 vf1 = __builtin_shufflevector(b0, b1, 0, 1, 2, 3, 4, 5, 6, 7);
                __builtin_amdgcn_s_setprio(1);
                acc[dp * 2 + 0] = __builtin_amdgcn_mfma_f32_16x16x32_f16(pf, vf0, acc[dp * 2 + 0], 0, 0, 0);
                acc[dp * 2 + 1] = __builtin_amdgcn_mfma_f32_16x16x32_f16(pf, vf1, acc[dp * 2 + 1], 0, 0, 0);
                __builtin_amdgcn_s_setprio(0);
            }
        }
        __syncthreads();
    }

    const float linv = 1.f / l;
    float inv[4];
    #pragma unroll
    for (int r = 0; r < 4; ++r) inv[r] = __shfl(linv, g * 20 + r);
    float* ob = Og + (size_t)(wave * 16) * DHEAD;
    #pragma unroll
    for (int dt = 0; dt < 8; ++dt)
        #pragma unroll
        for (int r = 0; r < 4; ++r)
            ob[(size_t)(g * 4 + r) * DHEAD + dt * 16 + lg] = acc[dt][r] * inv[r];
}

extern "C" void kernel_launch(void* const* d_in, const int* in_sizes, int n_in,
                              void* d_out, int out_size, void* d_ws, size_t ws_size,
                              hipStream_t stream) {
    const float* q = (const float*)d_in[0];
    const float* k = (const float*)d_in[1];
    const float* v = (const float*)d_in[2];
    float* out = (float*)d_out;
    const int BH = in_sizes[0] / (SEQ * DHEAD);   // 64

    const size_t elems = (size_t)BH * SEQ * DHEAD;           // 16M
    const size_t need  = elems * 2 * sizeof(_Float16);       // 64 MB
    if (ws_size >= need) {
        _Float16* Kp = (_Float16*)d_ws;
        _Float16* Vp = Kp + elems;
        preconv_kernel<<<dim3(BH * (SEQ / KVBLK)), dim3(256), 0, stream>>>(k, v, Kp, Vp);
        attn_fwd_kernel32<<<dim3(SEQ / 256, BH), dim3(512), 0, stream>>>(q, Kp, Vp, out);
    } else {
        attn_fwd_legacy<<<dim3(SEQ / 64, BH), dim3(256), 0, stream>>>(q, k, v, out);
    }
}